// Round 1
// baseline (139.152 us; speedup 1.0000x reference)
//
#include <hip/hip_runtime.h>

// B=2, N=96, D=64, H=4, DK=16
#define TENS   1179648   // floats per projected tensor (18432*64)
#define HM     147456    // floats per (b,h) head-major plane (9216*16)
#define T_ROWS 18432
#define NP_S   6         // a-split partial count (chunks of 16 a)

#define DOT16(A0,A1,A2,A3,B0,B1,B2,B3)                                   \
    fmaf(A3.w,B3.w, fmaf(A3.z,B3.z, fmaf(A3.y,B3.y, fmaf(A3.x,B3.x,     \
    fmaf(A2.w,B2.w, fmaf(A2.z,B2.z, fmaf(A2.y,B2.y, fmaf(A2.x,B2.x,     \
    fmaf(A1.w,B1.w, fmaf(A1.z,B1.z, fmaf(A1.y,B1.y, fmaf(A1.x,B1.x,     \
    fmaf(A0.w,B0.w, fmaf(A0.z,B0.z, fmaf(A0.y,B0.y, A0.x*B0.x)))))))))))))))

// ---------------------------------------------------------------------------
// proj4 v3 (verbatim R12): 288 blocks x 64 rows; all four matrices per block.
// ---------------------------------------------------------------------------
__global__ __launch_bounds__(256) void proj4_kernel(
    const float* __restrict__ state,
    const float* __restrict__ w0, const float* __restrict__ b0,
    const float* __restrict__ w1, const float* __restrict__ b1,
    const float* __restrict__ w2, const float* __restrict__ b2,
    const float* __restrict__ w3, const float* __restrict__ b3,
    float* __restrict__ o0, float* __restrict__ o1,
    float* __restrict__ o2, float* __restrict__ o3)
{
    __shared__ float swt[64 * 68];    // [k][c] transposed, current mat
    __shared__ float srow[64 * 68];   // [row][k], staged once
    __shared__ float sb[64];
    const int t = threadIdx.x;
    const int row0 = blockIdx.x * 64;

#pragma unroll
    for (int j = 0; j < 4; ++j) {          // stage 64 src rows once
        const int s = t + j * 256;
        const int row = s >> 4, k4 = s & 15;
        *(float4*)&srow[row * 68 + k4 * 4] =
            *(const float4*)(state + (size_t)(row0 + row) * 64 + k4 * 4);
    }
    const int b   = row0 / 9216;
    const int rb0 = row0 - b * 9216;
    const int c4 = t & 15, rg = t >> 4;
    const int h  = c4 >> 2;
    const int dq = c4 & 3;

    for (int mat = 0; mat < 4; ++mat) {
        const float* w  = (mat == 0) ? w0 : (mat == 1) ? w1 : (mat == 2) ? w2 : w3;
        const float* bi = (mat == 0) ? b0 : (mat == 1) ? b1 : (mat == 2) ? b2 : b3;
        float* o        = (mat == 0) ? o0 : (mat == 1) ? o1 : (mat == 2) ? o2 : o3;

        __syncthreads();
#pragma unroll
        for (int j = 0; j < 4; ++j) {      // stage W transposed
            const int s = t + j * 256;
            const int c = s >> 4, k4 = s & 15;
            const float4 wv = *(const float4*)(w + c * 64 + k4 * 4);
            swt[(k4 * 4 + 0) * 68 + c] = wv.x;
            swt[(k4 * 4 + 1) * 68 + c] = wv.y;
            swt[(k4 * 4 + 2) * 68 + c] = wv.z;
            swt[(k4 * 4 + 3) * 68 + c] = wv.w;
        }
        if (t < 64) sb[t] = bi[t];
        __syncthreads();

        const float4 binit = *(const float4*)&sb[c4 * 4];
        float4 acc[4];
#pragma unroll
        for (int rr = 0; rr < 4; ++rr) acc[rr] = binit;
#pragma unroll
        for (int k4 = 0; k4 < 16; ++k4) {
            const float4 wq0 = *(const float4*)&swt[(k4 * 4 + 0) * 68 + c4 * 4];
            const float4 wq1 = *(const float4*)&swt[(k4 * 4 + 1) * 68 + c4 * 4];
            const float4 wq2 = *(const float4*)&swt[(k4 * 4 + 2) * 68 + c4 * 4];
            const float4 wq3 = *(const float4*)&swt[(k4 * 4 + 3) * 68 + c4 * 4];
#pragma unroll
            for (int rr = 0; rr < 4; ++rr) {
                const float4 s4 = *(const float4*)&srow[(rg + rr * 16) * 68 + k4 * 4];
                acc[rr].x = fmaf(s4.x, wq0.x, acc[rr].x);
                acc[rr].y = fmaf(s4.x, wq0.y, acc[rr].y);
                acc[rr].z = fmaf(s4.x, wq0.z, acc[rr].z);
                acc[rr].w = fmaf(s4.x, wq0.w, acc[rr].w);
                acc[rr].x = fmaf(s4.y, wq1.x, acc[rr].x);
                acc[rr].y = fmaf(s4.y, wq1.y, acc[rr].y);
                acc[rr].z = fmaf(s4.y, wq1.z, acc[rr].z);
                acc[rr].w = fmaf(s4.y, wq1.w, acc[rr].w);
                acc[rr].x = fmaf(s4.z, wq2.x, acc[rr].x);
                acc[rr].y = fmaf(s4.z, wq2.y, acc[rr].y);
                acc[rr].z = fmaf(s4.z, wq2.z, acc[rr].z);
                acc[rr].w = fmaf(s4.z, wq2.w, acc[rr].w);
                acc[rr].x = fmaf(s4.w, wq3.x, acc[rr].x);
                acc[rr].y = fmaf(s4.w, wq3.y, acc[rr].y);
                acc[rr].z = fmaf(s4.w, wq3.z, acc[rr].z);
                acc[rr].w = fmaf(s4.w, wq3.w, acc[rr].w);
            }
        }
        float* dp = o + (size_t)(b * 4 + h) * HM + dq * 4;
#pragma unroll
        for (int rr = 0; rr < 4; ++rr)
            *(float4*)(dp + (size_t)(rb0 + rg + rr * 16) * 16) = acc[rr];
    }
}

// ---------------------------------------------------------------------------
// Fused attention v5: 3x3 register micro-tile on 48x24 (x,y) tiles.
// LDS b128 reads drop from 8 to 5.33 per (output, a). Grid 384 x 128 thr,
// 2 waves/block, ~41.5 KB LDS -> ~3 blocks/CU co-resident (hides staging).
// Same NP_S=6 a-slicing and partial layout as v4: proj1 unchanged, and the
// per-slice summation order over a is identical (numerics preserved).
// ---------------------------------------------------------------------------
__global__ __launch_bounds__(128, 1) void fused_attn_kernel(
    const float* __restrict__ lk, const float* __restrict__ rk,
    const float* __restrict__ lv, const float* __restrict__ rv,
    float* __restrict__ nump, float* __restrict__ denp)
{
    __shared__ float lk_s[48 * 68];      // [x-slot][4a*16d], pitch 68
    __shared__ float lv_s[48 * 68];
    __shared__ float rk_s[4 * 24 * 20];  // [ai][y-slot][16d], pitch 20
    __shared__ float rv_s[4 * 24 * 20];

    const int t = threadIdx.x;
    const int j = blockIdx.x;            // 0..383
    const int bh = j & 7;
    const int r2 = j >> 3;               // 0..47
    const int sc = r2 % 6;               // a-slice (16 a each)
    const int tile = r2 / 6;             // 0..7
    const int xt = tile & 1, yt = tile >> 1;
    const int x0 = xt * 48, y0 = yt * 24;
    const int a0 = sc * 16;
    const int xi = t & 15, yi = t >> 4;  // xi 0..15, yi 0..7

    const float* plk = lk + (size_t)bh * HM;
    const float* prk = rk + (size_t)bh * HM;
    const float* plv = lv + (size_t)bh * HM;
    const float* prv = rv + (size_t)bh * HM;

    float4 acc[3][3][4];
    float  den[3][3];
#pragma unroll
    for (int i = 0; i < 3; ++i)
#pragma unroll
        for (int jc = 0; jc < 3; ++jc) {
            den[i][jc] = 0.f;
#pragma unroll
            for (int q = 0; q < 4; ++q)
                acc[i][jc][q] = make_float4(0.f, 0.f, 0.f, 0.f);
        }

    for (int acx = 0; acx < 4; ++acx) {
        const int abase = a0 + acx * 4;
        __syncthreads();                 // LDS free (previous sub-tile consumed)
        // stage lk/lv: 48 x-rows * 4 a * 16 d  (6 float4 per thread per tensor)
#pragma unroll
        for (int jj = 0; jj < 6; ++jj) {
            const int s = t + jj * 128;
            const int xl = s >> 4, rem = s & 15, ai = rem >> 2, c = rem & 3;
            const size_t g = ((size_t)(x0 + xl) * 96 + abase + ai) * 16 + c * 4;
            const int lo = xl * 68 + ai * 16 + c * 4;
            *(float4*)&lk_s[lo] = *(const float4*)(plk + g);
            *(float4*)&lv_s[lo] = *(const float4*)(plv + g);
        }
        // stage rk/rv: 4 a * 24 y * 16 d (padded slot map, guard yl<24)
#pragma unroll
        for (int jj = 0; jj < 4; ++jj) {
            const int s = t + jj * 128;
            const int ai = s >> 7, rem = s & 127, yl = rem >> 2, c = rem & 3;
            if (yl < 24) {
                const size_t g = ((size_t)(abase + ai) * 96 + y0 + yl) * 16 + c * 4;
                const int ro = ai * 480 + yl * 20 + c * 4;
                *(float4*)&rk_s[ro] = *(const float4*)(prk + g);
                *(float4*)&rv_s[ro] = *(const float4*)(prv + g);
            }
        }
        __syncthreads();                 // LDS ready

#pragma unroll
        for (int asel = 0; asel < 4; ++asel) {
            // ---- score phase: 3 lk rows live, stream rk cols ----
            float4 ka[3][4];
#pragma unroll
            for (int i = 0; i < 3; ++i) {
                const int lo = (xi + 16 * i) * 68 + asel * 16;
#pragma unroll
                for (int q = 0; q < 4; ++q)
                    ka[i][q] = *(const float4*)&lk_s[lo + q * 4];
            }
            float p[3][3];
#pragma unroll
            for (int jc = 0; jc < 3; ++jc) {
                const int ro = asel * 480 + (yi + 8 * jc) * 20;
                const float4 q0 = *(const float4*)&rk_s[ro];
                const float4 q1 = *(const float4*)&rk_s[ro + 4];
                const float4 q2 = *(const float4*)&rk_s[ro + 8];
                const float4 q3 = *(const float4*)&rk_s[ro + 12];
#pragma unroll
                for (int i = 0; i < 3; ++i) {
                    const float sv = DOT16(ka[i][0], ka[i][1], ka[i][2], ka[i][3],
                                           q0, q1, q2, q3);
                    const float pv = __expf(sv * 0.25f);   // 1/sqrt(16); |s| << 1
                    p[i][jc] = pv;
                    den[i][jc] += pv;
                }
            }
            // ---- PV phase: 3 lv rows live (reuse ka regs), stream rv cols ----
            float4 la[3][4];
#pragma unroll
            for (int i = 0; i < 3; ++i) {
                const int lo = (xi + 16 * i) * 68 + asel * 16;
#pragma unroll
                for (int q = 0; q < 4; ++q)
                    la[i][q] = *(const float4*)&lv_s[lo + q * 4];
            }
#pragma unroll
            for (int jc = 0; jc < 3; ++jc) {
                const int ro = asel * 480 + (yi + 8 * jc) * 20;
                const float4 v0 = *(const float4*)&rv_s[ro];
                const float4 v1 = *(const float4*)&rv_s[ro + 4];
                const float4 v2 = *(const float4*)&rv_s[ro + 8];
                const float4 v3 = *(const float4*)&rv_s[ro + 12];
#pragma unroll
                for (int i = 0; i < 3; ++i) {
                    const float pp = p[i][jc];
                    acc[i][jc][0].x = fmaf(pp * la[i][0].x, v0.x, acc[i][jc][0].x);
                    acc[i][jc][0].y = fmaf(pp * la[i][0].y, v0.y, acc[i][jc][0].y);
                    acc[i][jc][0].z = fmaf(pp * la[i][0].z, v0.z, acc[i][jc][0].z);
                    acc[i][jc][0].w = fmaf(pp * la[i][0].w, v0.w, acc[i][jc][0].w);
                    acc[i][jc][1].x = fmaf(pp * la[i][1].x, v1.x, acc[i][jc][1].x);
                    acc[i][jc][1].y = fmaf(pp * la[i][1].y, v1.y, acc[i][jc][1].y);
                    acc[i][jc][1].z = fmaf(pp * la[i][1].z, v1.z, acc[i][jc][1].z);
                    acc[i][jc][1].w = fmaf(pp * la[i][1].w, v1.w, acc[i][jc][1].w);
                    acc[i][jc][2].x = fmaf(pp * la[i][2].x, v2.x, acc[i][jc][2].x);
                    acc[i][jc][2].y = fmaf(pp * la[i][2].y, v2.y, acc[i][jc][2].y);
                    acc[i][jc][2].z = fmaf(pp * la[i][2].z, v2.z, acc[i][jc][2].z);
                    acc[i][jc][2].w = fmaf(pp * la[i][2].w, v2.w, acc[i][jc][2].w);
                    acc[i][jc][3].x = fmaf(pp * la[i][3].x, v3.x, acc[i][jc][3].x);
                    acc[i][jc][3].y = fmaf(pp * la[i][3].y, v3.y, acc[i][jc][3].y);
                    acc[i][jc][3].z = fmaf(pp * la[i][3].z, v3.z, acc[i][jc][3].z);
                    acc[i][jc][3].w = fmaf(pp * la[i][3].w, v3.w, acc[i][jc][3].w);
                }
            }
        }
    }

    const size_t pb = (size_t)(sc * 8 + bh) * 9216;
#pragma unroll
    for (int i = 0; i < 3; ++i) {
#pragma unroll
        for (int jc = 0; jc < 3; ++jc) {
            const size_t rb = pb + (size_t)(x0 + xi + 16 * i) * 96 + (y0 + yi + 8 * jc);
            float4* np = (float4*)(nump + rb * 16);
            np[0] = acc[i][jc][0]; np[1] = acc[i][jc][1];
            np[2] = acc[i][jc][2]; np[3] = acc[i][jc][3];
            denp[rb] = den[i][jc];
        }
    }
}

// ---------------------------------------------------------------------------
// proj1 v3 (verbatim R12): 288 blocks x 64 rows; gather 6 partials + GEMM.
// ---------------------------------------------------------------------------
__global__ __launch_bounds__(256) void proj1_kernel(
    const float* __restrict__ nump, const float* __restrict__ denp,
    const float* __restrict__ w, const float* __restrict__ bi,
    float* __restrict__ out)
{
    __shared__ float swt[64 * 68];
    __shared__ float srow[64 * 68];
    __shared__ float sb[64];
    const int t = threadIdx.x;
    const int row0 = blockIdx.x * 64;
    const int bb  = row0 / 9216;
    const int rb0 = row0 - bb * 9216;

#pragma unroll
    for (int j = 0; j < 4; ++j) {          // stage w_out transposed
        const int s = t + j * 256;
        const int c = s >> 4, k4 = s & 15;
        const float4 wv = *(const float4*)(w + c * 64 + k4 * 4);
        swt[(k4 * 4 + 0) * 68 + c] = wv.x;
        swt[(k4 * 4 + 1) * 68 + c] = wv.y;
        swt[(k4 * 4 + 2) * 68 + c] = wv.z;
        swt[(k4 * 4 + 3) * 68 + c] = wv.w;
    }
#pragma unroll
    for (int j = 0; j < 4; ++j) {          // gather 64 rows from partials
        const int s = t + j * 256;
        const int rl = s >> 4, hc = s & 15;
        const int bh = bb * 4 + (hc >> 2);
        const int c4g = hc & 3;
        const int rb = rb0 + rl;
        float sx = 0.f, sy = 0.f, sz = 0.f, sw4 = 0.f, dd = 0.f;
#pragma unroll
        for (int sc = 0; sc < NP_S; ++sc) {
            const size_t rbs = (size_t)(sc * 8 + bh) * 9216 + rb;
            const float4 v = *(const float4*)(nump + rbs * 16 + c4g * 4);
            sx += v.x; sy += v.y; sz += v.z; sw4 += v.w;
            dd += denp[rbs];
        }
        const float inv = 1.0f / dd;
        float4 ov; ov.x = sx * inv; ov.y = sy * inv; ov.z = sz * inv; ov.w = sw4 * inv;
        *(float4*)&srow[rl * 68 + hc * 4] = ov;
    }
    if (t < 64) sb[t] = bi[t];
    __syncthreads();

    const int c4 = t & 15, rg = t >> 4;
    const float4 binit = *(const float4*)&sb[c4 * 4];
    float4 acc[4];
#pragma unroll
    for (int rr = 0; rr < 4; ++rr) acc[rr] = binit;
#pragma unroll
    for (int k4 = 0; k4 < 16; ++k4) {
        const float4 wq0 = *(const float4*)&swt[(k4 * 4 + 0) * 68 + c4 * 4];
        const float4 wq1 = *(const float4*)&swt[(k4 * 4 + 1) * 68 + c4 * 4];
        const float4 wq2 = *(const float4*)&swt[(k4 * 4 + 2) * 68 + c4 * 4];
        const float4 wq3 = *(const float4*)&swt[(k4 * 4 + 3) * 68 + c4 * 4];
#pragma unroll
        for (int rr = 0; rr < 4; ++rr) {
            const float4 s4 = *(const float4*)&srow[(rg + rr * 16) * 68 + k4 * 4];
            acc[rr].x = fmaf(s4.x, wq0.x, acc[rr].x);
            acc[rr].y = fmaf(s4.x, wq0.y, acc[rr].y);
            acc[rr].z = fmaf(s4.x, wq0.z, acc[rr].z);
            acc[rr].w = fmaf(s4.x, wq0.w, acc[rr].w);
            acc[rr].x = fmaf(s4.y, wq1.x, acc[rr].x);
            acc[rr].y = fmaf(s4.y, wq1.y, acc[rr].y);
            acc[rr].z = fmaf(s4.y, wq1.z, acc[rr].z);
            acc[rr].w = fmaf(s4.y, wq1.w, acc[rr].w);
            acc[rr].x = fmaf(s4.z, wq2.x, acc[rr].x);
            acc[rr].y = fmaf(s4.z, wq2.y, acc[rr].y);
            acc[rr].z = fmaf(s4.z, wq2.z, acc[rr].z);
            acc[rr].w = fmaf(s4.z, wq2.w, acc[rr].w);
            acc[rr].x = fmaf(s4.w, wq3.x, acc[rr].x);
            acc[rr].y = fmaf(s4.w, wq3.y, acc[rr].y);
            acc[rr].z = fmaf(s4.w, wq3.z, acc[rr].z);
            acc[rr].w = fmaf(s4.w, wq3.w, acc[rr].w);
        }
    }
#pragma unroll
    for (int rr = 0; rr < 4; ++rr)
        *(float4*)(out + (size_t)(row0 + rg + rr * 16) * 64 + c4 * 4) = acc[rr];
}

extern "C" void kernel_launch(void* const* d_in, const int* in_sizes, int n_in,
                              void* d_out, int out_size, void* d_ws, size_t ws_size,
                              hipStream_t stream)
{
    const float* state = (const float*)d_in[0];
    const float* w_lk  = (const float*)d_in[1];
    const float* b_lk  = (const float*)d_in[2];
    const float* w_rk  = (const float*)d_in[3];
    const float* b_rk  = (const float*)d_in[4];
    const float* w_lv  = (const float*)d_in[5];
    const float* b_lv  = (const float*)d_in[6];
    const float* w_rv  = (const float*)d_in[7];
    const float* b_rv  = (const float*)d_in[8];
    const float* w_out = (const float*)d_in[9];
    const float* b_out = (const float*)d_in[10];
    float* out = (float*)d_out;

    float* ws = (float*)d_ws;
    float* lk   = ws;                         // head-major [bh][row][16]
    float* rk   = ws + (size_t)TENS;
    float* lv   = ws + (size_t)2 * TENS;
    float* rv   = ws + (size_t)3 * TENS;
    float* nump = ws + (size_t)4 * TENS;      // 28.3 MB partials
    float* denp = nump + (size_t)NP_S * 8 * 9216 * 16;

    proj4_kernel<<<T_ROWS / 64, 256, 0, stream>>>(
        state, w_lk, b_lk, w_rk, b_rk, w_lv, b_lv, w_rv, b_rv, lk, rk, lv, rv);
    fused_attn_kernel<<<384, 128, 0, stream>>>(lk, rk, lv, rv, nump, denp);
    proj1_kernel<<<T_ROWS / 64, 256, 0, stream>>>(nump, denp, w_out, b_out, out);
}